// Round 18
// baseline (53.721 us; speedup 1.0000x reference)
//
#include <hip/hip_runtime.h>

// Chamfer loss: B=4, N=M=8192, D=3, fp32 in, scalar fp32 out.
// loss = mean_n min_m ||x_n-y_m||^2 + mean_m min_n ||...||^2 + lambda*bpp
//
// R17: ONE pass computes BOTH directions (row-min -> cham_x, col-min ->
// cham_y), halving MFMA count 524288 -> 262144. Evidence: pass pinned
// ~30us across R6..R16 with occupancy (R11), merge VALU (R12), unique
// bytes (R15), VMEM instrs (R16) all individually refuted; the only
// untouched invariant is MFMA count (~35cy effective each).
// MFMA output = complete d^2 (both norms folded in), K=10 of 16:
//   k0-5: -2a_d*(yhi_d|ylo_d)  k6-7: 1*(n2hi|n2lo)  k8-9: (x2hi|x2lo)*1
// a = bf16(x) query; y kept ~exact (hi/lo); x2=||a||^2, n2=||y||^2 hi/lo.
// A-frag row=lane&31, k-octet=lane>>5; C/D col=lane&31,
// row=(q&3)+8*(q>>2)+4*(lane>>5)  [verified since R6].
// Per tile: 1 MFMA; row-merge (paired min3 into racc); col-merge
// (16-reg fmin tree + shfl_xor(32)) -> per-wave LDS plane (bank-clean),
// block-combined into [b][seg][rowblk][1024] partials (8MB).
// reduce1: 8-way seg min (rows) + 64-way rowblk min (cols), sum both.

typedef float  f16v __attribute__((ext_vector_type(16)));
typedef short  s8   __attribute__((ext_vector_type(8)));

#define NPTS   8192
#define NB     4
#define NPTOT  (NB * NPTS)        // 32768 points per cloud
#define NSEG   8                  // column segments of 1024
#define SEGC   1024
#define NRB    64                 // row-blocks (128 rows each)
#define RBLK   128

__device__ __forceinline__ ushort f2bf(float f) {
    uint u = __float_as_uint(f);
    u += 0x7FFF + ((u >> 16) & 1);          // round-to-nearest-even
    return (ushort)(u >> 16);
}
__device__ __forceinline__ float bf2f(ushort h) {
    return __uint_as_float(((uint)h) << 16);
}
__device__ __forceinline__ uint pk(ushort lo, ushort hi) {
    return (uint)lo | ((uint)hi << 16);
}

// prep: point i of X -> Arec[2i..2i+1]; point i of Y -> Brec[2i..2i+1].
__global__ __launch_bounds__(256) void prep(
        const float* __restrict__ X, const float* __restrict__ Y,
        uint4* __restrict__ Arec, uint4* __restrict__ Brec) {
    int i = blockIdx.x * 256 + threadIdx.x;
    if (i >= NPTOT) return;
    const ushort ONE = 0x3F80;

    // A-side (query a = bf16(x)); x2 = ||a||^2 split hi/lo
    float x0 = X[3*i], x1 = X[3*i+1], x2c = X[3*i+2];
    ushort a0 = f2bf(x0), a1 = f2bf(x1), a2 = f2bf(x2c);
    float f0 = bf2f(a0), f1 = bf2f(a1), f2v = bf2f(a2);
    ushort m0 = f2bf(-2.0f * f0), m1 = f2bf(-2.0f * f1), m2 = f2bf(-2.0f * f2v);
    float q2 = __fmaf_rn(f0, f0, __fmaf_rn(f1, f1, f2v * f2v));
    ushort q2h = f2bf(q2), q2l = f2bf(q2 - bf2f(q2h));
    Arec[2*i]   = make_uint4(pk(m0,m1), pk(m2,m0), pk(m1,m2), pk(ONE,ONE));
    Arec[2*i+1] = make_uint4(pk(q2h,q2l), 0, 0, 0);

    // B-side (target y ~exact via hi/lo); n2 = ||y||^2 split hi/lo
    float y0 = Y[3*i], y1 = Y[3*i+1], y2c = Y[3*i+2];
    ushort b0 = f2bf(y0), b1 = f2bf(y1), b2 = f2bf(y2c);
    ushort l0 = f2bf(y0 - bf2f(b0)), l1 = f2bf(y1 - bf2f(b1));
    ushort l2 = f2bf(y2c - bf2f(b2));
    float n2 = __fmaf_rn(y0, y0, __fmaf_rn(y1, y1, y2c * y2c));
    ushort nh = f2bf(n2), nl = f2bf(n2 - bf2f(nh));
    Brec[2*i]   = make_uint4(pk(b0,b1), pk(b2,l0), pk(l1,l2), pk(nh,nl));
    Brec[2*i+1] = make_uint4(pk(ONE,ONE), 0, 0, 0);
}

#define LOADP(P, p)                                                          \
    P[0] = *(const s8*)&Brec[((size_t)bbase + (size_t)(2*(p))*32 + col)*2 + krec]; \
    P[1] = *(const s8*)&Brec[((size_t)bbase + (size_t)(2*(p)+1)*32 + col)*2 + krec];

#define TREE16(m, A)                                                         \
    {                                                                        \
        float t0 = fminf(A[0], A[1]),  t1 = fminf(A[2], A[3]);               \
        float t2 = fminf(A[4], A[5]),  t3 = fminf(A[6], A[7]);               \
        float t4 = fminf(A[8], A[9]),  t5 = fminf(A[10], A[11]);             \
        float t6 = fminf(A[12], A[13]), t7 = fminf(A[14], A[15]);            \
        t0 = fminf(t0, t1); t2 = fminf(t2, t3);                              \
        t4 = fminf(t4, t5); t6 = fminf(t6, t7);                              \
        t0 = fminf(t0, t2); t4 = fminf(t4, t6);                              \
        m = fminf(t0, t4);                                                   \
    }

#define COMP(P, p)                                                           \
    {                                                                        \
        f16v acc0 = __builtin_amdgcn_mfma_f32_32x32x16_bf16(                 \
            afrag, P[0], zero16, 0, 0, 0);                                   \
        f16v acc1 = __builtin_amdgcn_mfma_f32_32x32x16_bf16(                 \
            afrag, P[1], zero16, 0, 0, 0);                                   \
        _Pragma("unroll")                                                    \
        for (int q = 0; q < 16; q++)                                         \
            racc[q] = fminf(fminf(acc0[q], acc1[q]), racc[q]);               \
        float m0; TREE16(m0, acc0);                                          \
        m0 = fminf(m0, __shfl_xor(m0, 32, 64));                              \
        cmin[wave][(2*(p)) * 32 + col] = m0;                                 \
        float m1; TREE16(m1, acc1);                                          \
        m1 = fminf(m1, __shfl_xor(m1, 32, 64));                              \
        cmin[wave][(2*(p)+1) * 32 + col] = m1;                               \
    }

__global__ __launch_bounds__(256) void mfma_pass(
        const uint4* __restrict__ Arec, const uint4* __restrict__ Brec,
        float* __restrict__ minsP, float* __restrict__ colpart) {
    // grid = 2048: b(4) x rowblk(64) x seg(8); 4 waves; wave = 32 rows
    int bid    = blockIdx.x;
    int b      = bid >> 9;
    int rem    = bid & 511;
    int rowblk = rem >> 3;
    int seg    = rem & 7;
    int lane   = threadIdx.x & 63;
    int wave   = threadIdx.x >> 6;
    int col    = lane & 31;
    int krec   = lane >> 5;
    int rowbase = rowblk * 128 + wave * 32;

    // A fragment (rows = X): both octets real (k0-7 / k8-15)
    s8 afrag = *(const s8*)&Arec[((size_t)b * NPTS + rowbase + col) * 2 + krec];

    size_t bbase = (size_t)b * NPTS + (size_t)seg * SEGC;

    __shared__ float cmin[4][SEGC];   // per-wave col-min planes (16 KB)

    const f16v zero16 = {0,0,0,0,0,0,0,0,0,0,0,0,0,0,0,0};
    f16v racc;
#pragma unroll
    for (int q = 0; q < 16; q++) racc[q] = 3.0e38f;

    // 16 tile-pairs, ping-pong prefetch
    s8 PA[2], PB[2];
    LOADP(PA, 0);
    for (int p = 0; p < 14; p += 2) {
        LOADP(PB, p + 1);
        COMP(PA, p);
        LOADP(PA, p + 2);
        COMP(PB, p + 1);
    }
    LOADP(PB, 15);
    COMP(PA, 14);
    COMP(PB, 15);

    // x-direction: row-min across 32 cols (lane bits 0-4)
#pragma unroll
    for (int q = 0; q < 16; q++) {
        float v = racc[q];
        v = fminf(v, __shfl_xor(v, 1, 64));
        v = fminf(v, __shfl_xor(v, 2, 64));
        v = fminf(v, __shfl_xor(v, 4, 64));
        v = fminf(v, __shfl_xor(v, 8, 64));
        v = fminf(v, __shfl_xor(v, 16, 64));
        racc[q] = v;
    }
    if (col == 0) {
        float* dst = minsP + (size_t)seg * NPTOT + (size_t)b * NPTS + rowbase;
        int half = lane >> 5;
#pragma unroll
        for (int q = 0; q < 16; q++)
            dst[(q & 3) + 8 * (q >> 2) + 4 * half] = racc[q];
    }

    // y-direction: combine the 4 wave planes -> per-(block) col partials
    __syncthreads();
    int tid = threadIdx.x;
    float* cp = colpart + (((size_t)b * NSEG + seg) * NRB + rowblk) * SEGC;
#pragma unroll
    for (int c0 = 0; c0 < SEGC; c0 += 256) {
        int c = c0 + tid;
        cp[c] = fminf(fminf(cmin[0][c], cmin[1][c]),
                      fminf(cmin[2][c], cmin[3][c]));
    }
}

__global__ __launch_bounds__(256) void reduce1(
        const float* __restrict__ minsP, const float* __restrict__ colpart,
        float2* __restrict__ out2) {
    __shared__ float s1[256], s2[256];
    int t = threadIdx.x;
    int i = blockIdx.x * 256 + t;           // 128 blocks x 256 == NPTOT
    int b = i >> 13;
    int p = i & (NPTS - 1);

    float sx = 3.0e38f;
#pragma unroll
    for (int s = 0; s < NSEG; s++)
        sx = fminf(sx, minsP[(size_t)s * NPTOT + i]);

    int seg = p >> 10, c = p & (SEGC - 1);
    const float* cp = colpart + (((size_t)b * NSEG + seg) * NRB) * SEGC + c;
    float sy = 3.0e38f;
#pragma unroll 8
    for (int r = 0; r < NRB; r++)
        sy = fminf(sy, cp[(size_t)r * SEGC]);

    s1[t] = sx; s2[t] = sy;
    __syncthreads();
    for (int s = 128; s > 0; s >>= 1) {
        if (t < s) { s1[t] += s1[t + s]; s2[t] += s2[t + s]; }
        __syncthreads();
    }
    if (t == 0) out2[blockIdx.x] = make_float2(s1[0], s2[0]);
}

__global__ __launch_bounds__(RBLK) void reduce2(
        const float2* __restrict__ p2,
        const float* __restrict__ bpp, const float* __restrict__ lam,
        float* __restrict__ out) {
    __shared__ float s[RBLK];
    int t = threadIdx.x;
    float2 p = p2[t];
    s[t] = p.x + p.y;
    __syncthreads();
    for (int h = RBLK / 2; h > 0; h >>= 1) {
        if (t < h) s[t] += s[t + h];
        __syncthreads();
    }
    if (t == 0) out[0] = s[0] * (1.0f / (float)NPTOT) + lam[0] * bpp[0];
}

extern "C" void kernel_launch(void* const* d_in, const int* in_sizes, int n_in,
                              void* d_out, int out_size, void* d_ws, size_t ws_size,
                              hipStream_t stream) {
    const float* X   = (const float*)d_in[0];   // pc_pred  [4,8192,3]
    const float* Y   = (const float*)d_in[1];   // pc_target[4,8192,3]
    const float* bpp = (const float*)d_in[2];
    const float* lam = (const float*)d_in[3];
    float* out = (float*)d_out;

    char* w = (char*)d_ws;
    float2* p2      = (float2*)w;               w += 1024;
    float*  minsP   = (float*)w;                w += (size_t)NSEG * NPTOT * sizeof(float);
    float*  colpart = (float*)w;                w += (size_t)NB * NSEG * NRB * SEGC * sizeof(float);
    uint4*  Arec    = (uint4*)w;                w += (size_t)2 * NPTOT * sizeof(uint4);
    uint4*  Brec    = (uint4*)w;

    prep<<<NPTOT / 256, 256, 0, stream>>>(X, Y, Arec, Brec);
    mfma_pass<<<NB * NRB * NSEG, 256, 0, stream>>>(Arec, Brec, minsP, colpart);
    reduce1<<<NPTOT / 256, 256, 0, stream>>>(minsP, colpart, p2);
    reduce2<<<1, RBLK, 0, stream>>>(p2, bpp, lam, out);
}